// Round 6
// baseline (3366.549 us; speedup 1.0000x reference)
//
#include <hip/hip_runtime.h>

typedef unsigned short u16;
typedef unsigned int u32;
typedef __attribute__((ext_vector_type(8))) short bf16x8;
typedef __attribute__((ext_vector_type(4))) float f32x4;

#define TR 261888           // total anchor rows per batch image
#define LOGITS_OFF 0
#define PROBS_OFF  1047552  // 2*TR*2
#define DELTAS_OFF 2095104  // 2*(2*TR*2)

// LDS map (u16 indices). Conv phase: A halo [0,7920), Wchunk [8192,28672).
// Epilogue phase: Sh-half [0,16384), WT [16384,24832).
#define A_OFF  0
#define W_OFF  8192
#define SH_OFF 0
#define WT_OFF 16384
#define SMEM_U16 28672      // 57,344 B

__device__ __forceinline__ float b2f(u16 u) {
    union { u32 i; float f; } v; v.i = ((u32)u) << 16; return v.f;
}
__device__ __forceinline__ u16 f2b(float f) {
    union { float f; u32 i; } v; v.f = f;
    u32 x = v.i;
    return (u16)((x + 0x7fffu + ((x >> 16) & 1u)) >> 16);
}
__device__ __forceinline__ float bitsf(u32 b) {
    union { u32 i; float f; } v; v.i = b; return v.f;
}
__device__ __forceinline__ float ldmix(const void* p, int i, bool isb16) {
    return isb16 ? b2f(((const u16*)p)[i]) : ((const float*)p)[i];
}

// ---------------------------------------------------------------------------
// Single fused RPN head kernel. NO workspace, NO cross-kernel state.
// One block = 64 consecutive row-major pixels of one (level,batch).
// ---------------------------------------------------------------------------
__global__ __launch_bounds__(256, 2) void rpn_fused(
    const void* __restrict__ f0, const void* __restrict__ f1,
    const void* __restrict__ f2, const void* __restrict__ f3,
    const void* __restrict__ f4,
    const void* __restrict__ w3, const void* __restrict__ bsh,
    const void* __restrict__ wcls, const void* __restrict__ bcls,
    const void* __restrict__ wdelta, const void* __restrict__ bdelta,
    void* __restrict__ out)
{
    __shared__ u16 SMEM[SMEM_U16];

    const int tid  = threadIdx.x;
    const int wv   = tid >> 6;
    const int lane = tid & 63;
    const int quad = lane >> 4;
    const int l16  = lane & 15;

    // dtype flag, computed per-wave (every wave sees identical data -> uniform)
    {
    }
    const u16* f0u = (const u16*)f0;
    const u16 pv = f0u[lane * 2];
    const int pe = (pv >> 7) & 0xFF;
    const unsigned long long bm = __ballot(pe >= 90 && pe <= 140);
    const bool isb16 = (__popcll(bm) >= 48);

    // level decode (uniform per block)
    const int bid = blockIdx.x;
    const int lvl = (bid >= 2048) + (bid >= 2560) + (bid >= 2688) + (bid >= 2720);
    const int tileBase = (lvl == 0) ? 0 : (lvl == 1) ? 2048 : (lvl == 2) ? 2560
                        : (lvl == 3) ? 2688 : 2720;
    const int logS   = 8 - lvl;
    const int S      = 1 << logS;
    const int rowOff = (lvl == 0) ? 0 : (lvl == 1) ? 196608 : (lvl == 2) ? 245760
                      : (lvl == 3) ? 258048 : 261120;
    const void* feat = (lvl == 0) ? f0 : (lvl == 1) ? f1 : (lvl == 2) ? f2
                      : (lvl == 3) ? f3 : f4;
    const int tile = bid - tileBase;

    const int logC = (logS > 6) ? 6 : logS;    // strip: R rows x C cols
    const int C    = 1 << logC;
    const int hden = C + 2;                    // 66 / 34 / 18
    const int R    = 1 << (6 - logC);
    const int HP   = (R + 2) * hden;           // 198 / 136 / 108
    const int units = HP * 4;
    const int magic = (hden == 66) ? 993 : (hden == 34) ? 1928 : 3641; // hpx/hden

    const int P0  = tile * 64;
    const int b   = P0 >> (2 * logS);
    const int pin = P0 & ((1 << (2 * logS)) - 1);
    const int h0  = pin >> logS;
    const int w0  = pin & (S - 1);

    const f32x4 zf = {0.f, 0.f, 0.f, 0.f};
    f32x4 acc[4][8];
#pragma unroll
    for (int mt = 0; mt < 4; ++mt)
#pragma unroll
        for (int nt = 0; nt < 8; ++nt) acc[mt][nt] = zf;

    // ================= conv K loop: 8 ch-chunks x 9 taps =================
    for (int cc = 0; cc < 8; ++cc) {
        __syncthreads();                    // prior tap's A/W reads done

        // ---- stage A halo chunk: (R+2)x(C+2) px, 32 ch, stride 40 ----
#pragma unroll
        for (int it = 0; it < 4; ++it) {
            const int u = tid + it * 256;
            if (u < units) {
                const int ch8 = (u & 3) * 8;
                const int hpx = u >> 2;
                const int hr  = (hpx * magic) >> 16;
                const int hc  = hpx - hr * hden;
                const int h = h0 + hr - 1;
                const int w = w0 + hc - 1;
                uint4 v; v.x = 0u; v.y = 0u; v.z = 0u; v.w = 0u;
                if (h >= 0 && h < S && w >= 0 && w < S) {
                    const size_t g = ((size_t)((b * S + h) * S + w)) * 256 + cc * 32 + ch8;
                    if (isb16) {
                        v = *(const uint4*)((const u16*)feat + g);
                    } else {
                        const float* fp = (const float*)feat + g;
                        const uint4 a  = *(const uint4*)fp;
                        const uint4 c2 = *(const uint4*)(fp + 4);
                        v.x = (u32)f2b(bitsf(a.x))  | ((u32)f2b(bitsf(a.y))  << 16);
                        v.y = (u32)f2b(bitsf(a.z))  | ((u32)f2b(bitsf(a.w))  << 16);
                        v.z = (u32)f2b(bitsf(c2.x)) | ((u32)f2b(bitsf(c2.y)) << 16);
                        v.w = (u32)f2b(bitsf(c2.z)) | ((u32)f2b(bitsf(c2.w)) << 16);
                    }
                }
                *(uint4*)&SMEM[A_OFF + hpx * 40 + ch8] = v;
            }
        }

        for (int tap = 0; tap < 9; ++tap) {
            if (tap) __syncthreads();       // prior tap's W reads done

            // ---- stage W chunk (tap,cc): [512 n][40] padded, frag-order ----
            // element (k = jq*4+rr, n) -> octet (jq>>1)^(n&3), slot (jq&1)*4+rr
#pragma unroll
            for (int rep = 0; rep < 4; ++rep) {
                const int task = tid + rep * 256;          // 0..1023
                const int n4 = (task & 127) * 4;
                const int jq = task >> 7;                  // 0..7
                const int row0 = tap * 256 + cc * 32 + jq * 4;
                u16 vr[4][4];
#pragma unroll
                for (int rr = 0; rr < 4; ++rr) {
                    const size_t base = (size_t)(row0 + rr) * 512 + n4;
                    if (isb16) {
                        const ushort4 t = *(const ushort4*)&((const u16*)w3)[base];
                        vr[rr][0] = t.x; vr[rr][1] = t.y; vr[rr][2] = t.z; vr[rr][3] = t.w;
                    } else {
                        const f32x4 t = *(const f32x4*)&((const float*)w3)[base];
                        vr[rr][0] = f2b(t[0]); vr[rr][1] = f2b(t[1]);
                        vr[rr][2] = f2b(t[2]); vr[rr][3] = f2b(t[3]);
                    }
                }
#pragma unroll
                for (int i = 0; i < 4; ++i) {
                    const int n = n4 + i;
                    const int j2 = (((jq >> 1) ^ (n & 3)) << 3) + ((jq & 1) << 2);
                    *(uint2*)&SMEM[W_OFF + n * 40 + j2] =
                        make_uint2((u32)vr[0][i] | ((u32)vr[1][i] << 16),
                                   (u32)vr[2][i] | ((u32)vr[3][i] << 16));
                }
            }
            __syncthreads();

            // ---- fragments + MFMA ----
            const int dh = tap / 3 - 1, dw = tap % 3 - 1;
            bf16x8 bfr[8];
#pragma unroll
            for (int nt = 0; nt < 8; ++nt) {
                const int n = wv * 128 + nt * 16 + l16;
                const int oct = quad ^ (n & 3);
                bfr[nt] = *(const bf16x8*)&SMEM[W_OFF + n * 40 + oct * 8];
            }
#pragma unroll
            for (int mt = 0; mt < 4; ++mt) {
                const int r0 = (mt * 16) >> logC;
                const int c0 = (mt * 16 & (C - 1)) + l16;
                const int idx = A_OFF +
                    ((r0 + 1 + dh) * hden + (c0 + 1 + dw)) * 40 + quad * 8;
                bf16x8 af = *(const bf16x8*)&SMEM[idx];
#pragma unroll
                for (int nt = 0; nt < 8; ++nt)
                    acc[mt][nt] = __builtin_amdgcn_mfma_f32_16x16x32_bf16(
                        af, bfr[nt], acc[mt][nt], 0, 0, 0);
            }
        }
    }

    // ================= epilogue: bias+relu -> Sh, GEMM2 in 2 half-passes ====
    f32x4 a2[2];
    a2[0] = zf; a2[1] = zf;

    for (int h = 0; h < 2; ++h) {
        __syncthreads();                  // prior phase's LDS reads done
        // Sh-half: waves holding n in [h*256,(h+1)*256) write their acc
        if ((wv >> 1) == h) {
#pragma unroll
            for (int nt = 0; nt < 8; ++nt) {
                const int n = wv * 128 + nt * 16 + l16;
                const int nl = n & 255;
                const float bn = ldmix(bsh, n, isb16);
#pragma unroll
                for (int mt = 0; mt < 4; ++mt) {
#pragma unroll
                    for (int r = 0; r < 4; ++r) {
                        const int px = mt * 16 + quad * 4 + r;
                        float vv = acc[mt][nt][r] + bn;
                        vv = vv > 0.f ? vv : 0.f;
                        SMEM[SH_OFF + px * 256 + (nl ^ ((px & 3) * 8))] = f2b(vv);
                    }
                }
            }
        }
        // WT-half: [32 j][264 pad] bf16, rows 18..31 zero
        {
            const int chl = tid;          // 0..255
            const int ch  = h * 256 + chl;
#pragma unroll
            for (int j = 0; j < 32; ++j) {
                float v = 0.f;
                if (j < 6)       v = ldmix(wcls, ch * 6 + j, isb16);
                else if (j < 18) v = ldmix(wdelta, ch * 12 + (j - 6), isb16);
                SMEM[WT_OFF + j * 264 + chl] = f2b(v);
            }
        }
        __syncthreads();
        // GEMM2 partial: contract 256 ch of this half
#pragma unroll
        for (int jt = 0; jt < 2; ++jt) {
#pragma unroll
            for (int ks = 0; ks < 8; ++ks) {
                const int j = jt * 16 + l16;
                bf16x8 wa = *(const bf16x8*)&SMEM[WT_OFF + j * 264 + ks * 32 + quad * 8];
                const int px = wv * 16 + l16;
                const int c  = (ks * 32 + quad * 8) ^ ((px & 3) * 8);
                bf16x8 sb = *(const bf16x8*)&SMEM[SH_OFF + px * 256 + c];
                a2[jt] = __builtin_amdgcn_mfma_f32_16x16x32_bf16(wa, sb, a2[jt], 0, 0, 0);
            }
        }
    }

    // ---------------- outputs (paired float2 / u32 stores) ----------------
    const int Pimg = pin + wv * 16 + l16;
    const size_t rowBase = (size_t)b * TR + rowOff + (size_t)Pimg * 3;
    const size_t rb2 = rowBase * 2;
    const size_t rb4 = rowBase * 4;
    u16*   o16 = (u16*)out;
    float* o32 = (float*)out;
    auto st2 = [&](size_t elem, float v0, float v1) {   // elem always even
        if (isb16) {
            u32 p = (u32)f2b(v0) | ((u32)f2b(v1) << 16);
            *(u32*)&o16[elem] = p;
        } else {
            *(float2*)&o32[elem] = make_float2(v0, v1);
        }
    };
    auto smax = [&](float L0, float L1, float& P0, float& P1) {
        const float m = fmaxf(L0, L1);
        const float e0 = __expf(L0 - m), e1 = __expf(L1 - m);
        const float inv = 1.0f / (e0 + e1);
        P0 = e0 * inv; P1 = e1 * inv;
    };

    if (quad == 0) {
        float L0 = a2[0][0] + ldmix(bcls, 0, isb16);
        float L1 = a2[0][1] + ldmix(bcls, 1, isb16);
        float L2 = a2[0][2] + ldmix(bcls, 2, isb16);
        float L3 = a2[0][3] + ldmix(bcls, 3, isb16);
        st2(LOGITS_OFF + rb2 + 0, L0, L1);
        st2(LOGITS_OFF + rb2 + 2, L2, L3);
        float P0, P1, P2, P3;
        smax(L0, L1, P0, P1); smax(L2, L3, P2, P3);
        st2(PROBS_OFF + rb2 + 0, P0, P1);
        st2(PROBS_OFF + rb2 + 2, P2, P3);
        float d10 = a2[1][0] + ldmix(bdelta, 10, isb16);
        float d11 = a2[1][1] + ldmix(bdelta, 11, isb16);
        st2(DELTAS_OFF + rb4 + 10, d10, d11);
    } else if (quad == 1) {
        float L4 = a2[0][0] + ldmix(bcls, 4, isb16);
        float L5 = a2[0][1] + ldmix(bcls, 5, isb16);
        st2(LOGITS_OFF + rb2 + 4, L4, L5);
        float P4, P5; smax(L4, L5, P4, P5);
        st2(PROBS_OFF + rb2 + 4, P4, P5);
        float d0 = a2[0][2] + ldmix(bdelta, 0, isb16);
        float d1 = a2[0][3] + ldmix(bdelta, 1, isb16);
        st2(DELTAS_OFF + rb4 + 0, d0, d1);
    } else if (quad == 2) {
        float d2 = a2[0][0] + ldmix(bdelta, 2, isb16);
        float d3 = a2[0][1] + ldmix(bdelta, 3, isb16);
        float d4 = a2[0][2] + ldmix(bdelta, 4, isb16);
        float d5 = a2[0][3] + ldmix(bdelta, 5, isb16);
        st2(DELTAS_OFF + rb4 + 2, d2, d3);
        st2(DELTAS_OFF + rb4 + 4, d4, d5);
    } else {
        float d6 = a2[0][0] + ldmix(bdelta, 6, isb16);
        float d7 = a2[0][1] + ldmix(bdelta, 7, isb16);
        float d8 = a2[0][2] + ldmix(bdelta, 8, isb16);
        float d9 = a2[0][3] + ldmix(bdelta, 9, isb16);
        st2(DELTAS_OFF + rb4 + 6, d6, d7);
        st2(DELTAS_OFF + rb4 + 8, d8, d9);
    }
}

// ---------------------------------------------------------------------------
extern "C" void kernel_launch(void* const* d_in, const int* in_sizes, int n_in,
                              void* d_out, int out_size, void* d_ws, size_t ws_size,
                              hipStream_t stream) {
    // d_ws intentionally unused: all staging is in-kernel LDS.
    rpn_fused<<<2728, 256, 0, stream>>>(
        d_in[0], d_in[1], d_in[2], d_in[3], d_in[4],
        d_in[5], d_in[6], d_in[7], d_in[8], d_in[9], d_in[10],
        d_out);
}